// Round 8
// baseline (758.936 us; speedup 1.0000x reference)
//
#include <hip/hip_runtime.h>
#include <hip/hip_bf16.h>

#define N_NODES 50000
#define N_EDGES 800000
#define FDIM 256
#define N_LAYERS 3
#define NB_SCAN ((N_NODES + 255) / 256)

typedef __attribute__((ext_vector_type(8))) short bf16x8;
typedef __attribute__((ext_vector_type(8))) unsigned short u16x8;
typedef __attribute__((ext_vector_type(4))) float f32x4;

// RNE fp32 -> bf16 bit conversion (inputs finite)
__device__ inline unsigned short f2bf(float f) {
  unsigned int u = __float_as_uint(f);
  unsigned int r = u + 0x7FFFu + ((u >> 16) & 1u);
  return (unsigned short)(r >> 16);
}
__device__ inline float bf2f(unsigned short s) {
  return __uint_as_float(((unsigned int)s) << 16);
}
__device__ inline void split2(float f, unsigned short& h, unsigned short& l) {
  h = f2bf(f);
  l = f2bf(f - bf2f(h));
}

#define GLOAD16(g, l) __builtin_amdgcn_global_load_lds( \
    (const __attribute__((address_space(1))) void*)(g), \
    (__attribute__((address_space(3))) void*)(l), 16, 0, 0)

// ---------------- preprocessing (once per call; layer-invariant) ----------------

__global__ void deg_count_kernel(const int* __restrict__ dst,
                                 const float* __restrict__ w,
                                 float* __restrict__ deg,
                                 int* __restrict__ cnt, int E) {
  int e = blockIdx.x * blockDim.x + threadIdx.x;
  if (e < E) {
    int d = dst[e];
    atomicAdd(&deg[d], w[e]);
    atomicAdd(&cnt[d], 1);
  }
}

__global__ void dinv_kernel(const float* __restrict__ deg,
                            float* __restrict__ dinv, int n) {
  int i = blockIdx.x * blockDim.x + threadIdx.x;
  if (i < n) {
    float d = deg[i];
    dinv[i] = (d > 0.f) ? (1.f / sqrtf(d)) : 0.f;
  }
}

// multi-block scan: per-block sums -> 1-block scan of sums -> per-block offsets
__global__ __launch_bounds__(256)
void blocksum_kernel(const int* __restrict__ cnt, int* __restrict__ bsum, int n) {
  int b = blockIdx.x;
  int t = threadIdx.x;
  int i = b * 256 + t;
  int v = (i < n) ? cnt[i] : 0;
  #pragma unroll
  for (int d = 1; d < 64; d <<= 1) v += __shfl_xor(v, d, 64);
  __shared__ int ws[4];
  if ((t & 63) == 0) ws[t >> 6] = v;
  __syncthreads();
  if (t == 0) bsum[b] = ws[0] + ws[1] + ws[2] + ws[3];
}

__global__ __launch_bounds__(256)
void scanb_kernel(const int* __restrict__ bsum, int* __restrict__ bpre,
                  int* __restrict__ offs_end) {
  int t = threadIdx.x;
  int lane = t & 63, wid = t >> 6;
  int v = (t < NB_SCAN) ? bsum[t] : 0;
  int incl = v;
  #pragma unroll
  for (int d = 1; d < 64; d <<= 1) {
    int tmp = __shfl_up(incl, d, 64);
    if (lane >= d) incl += tmp;
  }
  __shared__ int wsum[4];
  if (lane == 63) wsum[wid] = incl;
  __syncthreads();
  if (t == 0) {
    int s = 0;
    #pragma unroll
    for (int k = 0; k < 4; ++k) { int tt = wsum[k]; wsum[k] = s; s += tt; }
  }
  __syncthreads();
  int excl = incl - v + wsum[wid];
  if (t < NB_SCAN) bpre[t] = excl;
  if (t == NB_SCAN - 1) *offs_end = excl + v;
}

__global__ __launch_bounds__(256)
void offs_kernel(const int* __restrict__ cnt, const int* __restrict__ bpre,
                 int* __restrict__ offs, int* __restrict__ cursor, int n) {
  int b = blockIdx.x;
  int t = threadIdx.x;
  int lane = t & 63, wid = t >> 6;
  int i = b * 256 + t;
  int v = (i < n) ? cnt[i] : 0;
  int incl = v;
  #pragma unroll
  for (int d = 1; d < 64; d <<= 1) {
    int tmp = __shfl_up(incl, d, 64);
    if (lane >= d) incl += tmp;
  }
  __shared__ int wsum[4];
  if (lane == 63) wsum[wid] = incl;
  __syncthreads();
  if (t == 0) {
    int s = 0;
    #pragma unroll
    for (int k = 0; k < 4; ++k) { int tt = wsum[k]; wsum[k] = s; s += tt; }
  }
  __syncthreads();
  int excl = incl - v + wsum[wid] + bpre[b];
  if (i < n) { offs[i] = excl; cursor[i] = excl; }
}

__global__ void scatter_kernel(const int* __restrict__ src,
                               const int* __restrict__ dst,
                               const float* __restrict__ w,
                               const float* __restrict__ dinv,
                               int* __restrict__ cursor,
                               int* __restrict__ src_s,
                               float* __restrict__ norm_s, int E) {
  int e = blockIdx.x * blockDim.x + threadIdx.x;
  if (e < E) {
    int s = src[e], d = dst[e];
    int pos = atomicAdd(&cursor[d], 1);
    src_s[pos] = s;
    norm_s[pos] = dinv[s] * w[e] * dinv[d];
  }
}

// split x0 -> hi/lo bf16
__global__ void split_kernel(const float* __restrict__ x,
                             unsigned short* __restrict__ xhi,
                             unsigned short* __restrict__ xlo, int n4) {
  int i = blockIdx.x * blockDim.x + threadIdx.x;
  if (i < n4) {
    float4 v = reinterpret_cast<const float4*>(x)[i];
    ushort4 h, l;
    split2(v.x, h.x, l.x);
    split2(v.y, h.y, l.y);
    split2(v.z, h.z, l.z);
    split2(v.w, h.w, l.w);
    reinterpret_cast<ushort4*>(xhi)[i] = h;
    reinterpret_cast<ushort4*>(xlo)[i] = l;
  }
}

// transpose + split weights: Wt[mat][n][k] = W[mat][k][n], mat = layer*2 + {Wi,Wr}
__global__ __launch_bounds__(256)
void wsplit_kernel(const float* __restrict__ Wi_a,
                   const float* __restrict__ Wr_a,
                   unsigned short* __restrict__ wthi,
                   unsigned short* __restrict__ wtlo) {
  __shared__ float tile[32][33];
  int m6 = blockIdx.x >> 6;            // 0..5
  int tid = blockIdx.x & 63;
  int tk = (tid >> 3) * 32;
  int tn = (tid & 7) * 32;
  int layer = m6 >> 1;
  const float* W = ((m6 & 1) ? Wr_a : Wi_a) + (size_t)layer * FDIM * FDIM;
  int t = threadIdx.x;
  int lr = t >> 3;            // 0..31
  int lc = (t & 7) * 4;       // 0..28
  float4 v = *reinterpret_cast<const float4*>(W + (size_t)(tk + lr) * FDIM + tn + lc);
  tile[lr][lc + 0] = v.x; tile[lr][lc + 1] = v.y;
  tile[lr][lc + 2] = v.z; tile[lr][lc + 3] = v.w;
  __syncthreads();
  ushort4 h, l;
  split2(tile[lc + 0][lr], h.x, l.x);
  split2(tile[lc + 1][lr], h.y, l.y);
  split2(tile[lc + 2][lr], h.z, l.z);
  split2(tile[lc + 3][lr], h.w, l.w);
  size_t o = ((size_t)m6 * FDIM + tn + lr) * FDIM + tk + lc;
  *reinterpret_cast<ushort4*>(wthi + o) = h;
  *reinterpret_cast<ushort4*>(wtlo + o) = l;
}

// ---------------- aggregation on x: aggx = A_norm @ x -------------------------
// 2 nodes per wave: 32 lanes x ushort8 (16B) per row -> 1KB per gather instr.
// fp32 accum; writes aggx as split hi/lo bf16.

__global__ __launch_bounds__(256)
void agg_kernel(const unsigned short* __restrict__ xh,
                const float* __restrict__ norm_s,
                const int* __restrict__ src_s,
                const int* __restrict__ offs,
                unsigned short* __restrict__ agh,
                unsigned short* __restrict__ agl, int n) {
  int t = threadIdx.x;
  int lane = t & 63;
  int node = blockIdx.x * 8 + ((t >> 6) << 1) + (lane >> 5);
  if (node >= n) return;
  int fl = lane & 31;                 // this lane owns feats [fl*8, fl*8+8)
  int beg = offs[node];
  int end = offs[node + 1];
  float a[8];
  #pragma unroll
  for (int f = 0; f < 8; ++f) a[f] = 0.f;
  int j = beg;
  for (; j + 4 <= end; j += 4) {
    int s0 = src_s[j], s1 = src_s[j + 1], s2 = src_s[j + 2], s3 = src_s[j + 3];
    float w0 = norm_s[j], w1 = norm_s[j + 1], w2 = norm_s[j + 2], w3 = norm_s[j + 3];
    u16x8 v0 = *reinterpret_cast<const u16x8*>(xh + (size_t)s0 * FDIM + fl * 8);
    u16x8 v1 = *reinterpret_cast<const u16x8*>(xh + (size_t)s1 * FDIM + fl * 8);
    u16x8 v2 = *reinterpret_cast<const u16x8*>(xh + (size_t)s2 * FDIM + fl * 8);
    u16x8 v3 = *reinterpret_cast<const u16x8*>(xh + (size_t)s3 * FDIM + fl * 8);
    #pragma unroll
    for (int f = 0; f < 8; ++f)
      a[f] += w0 * bf2f(v0[f]) + w1 * bf2f(v1[f]) +
              w2 * bf2f(v2[f]) + w3 * bf2f(v3[f]);
  }
  for (; j < end; ++j) {
    int s = src_s[j];
    float wv = norm_s[j];
    u16x8 v = *reinterpret_cast<const u16x8*>(xh + (size_t)s * FDIM + fl * 8);
    #pragma unroll
    for (int f = 0; f < 8; ++f) a[f] += wv * bf2f(v[f]);
  }
  u16x8 hh, ll;
  #pragma unroll
  for (int f = 0; f < 8; ++f) {
    unsigned short h, l;
    split2(a[f], h, l);
    hh[f] = h; ll[f] = l;
  }
  size_t base = (size_t)node * FDIM + fl * 8;
  *reinterpret_cast<u16x8*>(agh + base) = hh;
  *reinterpret_cast<u16x8*>(agl + base) = ll;
}

// ------- fused dual-A GEMM: xnext = relu(aggx@Wi + x@Wr + b), split output ----
// 128x128 tile, BK=32, 4 waves (2x2), 4x4 16x16x32 frags, 3-term split per side.
// A-side (agh/agl/xh/xl) double-buffered in LDS (2 x 32KB), XOR k-slot swizzle
// both sides. B-side (weights, L2-resident) loaded straight to registers each
// step BEFORE the A staging is issued, so B-use vmcnt waits don't drain staging.
// One __syncthreads per K-step (standard dbuf).

#define STAGE_TILE(BASE, TI, GPTR, K0)                                            \
  {                                                                               \
    int s0_ = t;                                                                  \
    int rr_ = s0_ >> 2;                                                           \
    int sl_ = (s0_ & 3) ^ ((rr_ >> 1) & 3);                                       \
    int r2_ = rowBase + rr_; if (r2_ >= M) r2_ = M - 1;                           \
    GLOAD16((GPTR) + (size_t)r2_ * FDIM + (K0) + sl_ * 8,                         \
            (BASE) + (TI) * 8192 + s0_ * 16);                                     \
    int s1_ = t + 256;                                                            \
    rr_ = s1_ >> 2;                                                               \
    sl_ = (s1_ & 3) ^ ((rr_ >> 1) & 3);                                           \
    r2_ = rowBase + rr_; if (r2_ >= M) r2_ = M - 1;                               \
    GLOAD16((GPTR) + (size_t)r2_ * FDIM + (K0) + sl_ * 8,                         \
            (BASE) + (TI) * 8192 + s1_ * 16);                                     \
  }

#define STAGE_A(BASE, K0)                  \
  STAGE_TILE(BASE, 0, agh, K0);            \
  STAGE_TILE(BASE, 1, agl, K0);            \
  STAGE_TILE(BASE, 2, xh, K0);             \
  STAGE_TILE(BASE, 3, xl, K0);

__global__ __launch_bounds__(256, 2)
void gemm_dual_kernel(const unsigned short* __restrict__ agh,
                      const unsigned short* __restrict__ agl,
                      const unsigned short* __restrict__ xh,
                      const unsigned short* __restrict__ xl,
                      const unsigned short* __restrict__ wih,
                      const unsigned short* __restrict__ wil,
                      const unsigned short* __restrict__ wrh,
                      const unsigned short* __restrict__ wrl,
                      const float* __restrict__ bias,
                      unsigned short* __restrict__ oh,
                      unsigned short* __restrict__ ol,
                      float* __restrict__ ofinal,
                      int writeFinal, int M) {
  __shared__ __align__(16) unsigned char smem[65536];   // 2 x 32KB A buffers
  const int t = threadIdx.x;
  const int lane = t & 63;
  const int w = t >> 6;
  const int bid = blockIdx.x;
  const int rowBase = (bid >> 1) * 128;
  const int nBase = (bid & 1) * 128;

  const int wm = (w >> 1) * 64;
  const int wn = (w & 1) * 64;
  const int q = lane >> 4;

  f32x4 acc[4][4];
  #pragma unroll
  for (int i = 0; i < 4; ++i)
    #pragma unroll
    for (int j = 0; j < 4; ++j)
      acc[i][j] = (f32x4)(0.f);

  // prologue: stage K-step 0 into buffer 0
  STAGE_A(smem, 0);

  for (int s = 0; s < 8; ++s) {
    __syncthreads();   // staging for this step landed; prev reads done
    unsigned char* cur = smem + (s & 1) * 32768;
    unsigned char* nxt = smem + ((s + 1) & 1) * 32768;
    const int k0 = s * 32;

    // B fragments straight from global (L2-resident weights), issued FIRST
    bf16x8 Bih[4], Bil[4], Brh[4], Brl[4];
    #pragma unroll
    for (int j = 0; j < 4; ++j) {
      size_t bo = (size_t)(nBase + wn + j * 16 + (lane & 15)) * FDIM + k0 + q * 8;
      Bih[j] = *reinterpret_cast<const bf16x8*>(wih + bo);
      Bil[j] = *reinterpret_cast<const bf16x8*>(wil + bo);
      Brh[j] = *reinterpret_cast<const bf16x8*>(wrh + bo);
      Brl[j] = *reinterpret_cast<const bf16x8*>(wrl + bo);
    }
    __builtin_amdgcn_sched_barrier(0);   // keep B-load issue ahead of staging

    if (s < 7) {
      STAGE_A(nxt, k0 + 32);             // flies under the MFMA work below
    }

    #pragma unroll
    for (int i = 0; i < 4; ++i) {
      int R = wm + i * 16 + (lane & 15);
      int offA = R * 64 + ((q ^ ((R >> 1) & 3)) * 16);
      bf16x8 fah = *reinterpret_cast<const bf16x8*>(cur + offA);
      bf16x8 fal = *reinterpret_cast<const bf16x8*>(cur + 8192 + offA);
      bf16x8 fxh = *reinterpret_cast<const bf16x8*>(cur + 16384 + offA);
      bf16x8 fxl = *reinterpret_cast<const bf16x8*>(cur + 24576 + offA);
      #pragma unroll
      for (int j = 0; j < 4; ++j) {
        acc[i][j] = __builtin_amdgcn_mfma_f32_16x16x32_bf16(fal, Bih[j], acc[i][j], 0, 0, 0);
        acc[i][j] = __builtin_amdgcn_mfma_f32_16x16x32_bf16(fah, Bil[j], acc[i][j], 0, 0, 0);
        acc[i][j] = __builtin_amdgcn_mfma_f32_16x16x32_bf16(fah, Bih[j], acc[i][j], 0, 0, 0);
        acc[i][j] = __builtin_amdgcn_mfma_f32_16x16x32_bf16(fxl, Brh[j], acc[i][j], 0, 0, 0);
        acc[i][j] = __builtin_amdgcn_mfma_f32_16x16x32_bf16(fxh, Brl[j], acc[i][j], 0, 0, 0);
        acc[i][j] = __builtin_amdgcn_mfma_f32_16x16x32_bf16(fxh, Brh[j], acc[i][j], 0, 0, 0);
      }
    }
  }

  const int cr = lane & 15;
  const int r4 = (lane >> 4) * 4;
  #pragma unroll
  for (int i = 0; i < 4; ++i)
    #pragma unroll
    for (int j = 0; j < 4; ++j) {
      int col = nBase + wn + j * 16 + cr;
      float badd = bias[col];
      #pragma unroll
      for (int e = 0; e < 4; ++e) {
        int row = rowBase + wm + i * 16 + r4 + e;
        if (row < M) {
          float val = fmaxf(acc[i][j][e] + badd, 0.f);
          size_t o = (size_t)row * FDIM + col;
          if (writeFinal) {
            ofinal[o] = val;
          } else {
            unsigned short hh, ll;
            split2(val, hh, ll);
            oh[o] = hh;
            ol[o] = ll;
          }
        }
      }
    }
}

// ---------------- launch ----------------

extern "C" void kernel_launch(void* const* d_in, const int* in_sizes, int n_in,
                              void* d_out, int out_size, void* d_ws, size_t ws_size,
                              hipStream_t stream) {
  (void)in_sizes; (void)n_in; (void)out_size; (void)ws_size;
  const float* x0   = (const float*)d_in[0];
  const int*   ei   = (const int*)d_in[1];
  const float* ea   = (const float*)d_in[2];
  const float* Wi_a = (const float*)d_in[3];
  const float* Wr_a = (const float*)d_in[4];
  const float* b_a  = (const float*)d_in[5];
  float* out = (float*)d_out;

  const int* src = ei;
  const int* dst = ei + N_EDGES;

  char* ws = (char*)d_ws;
  size_t off = 0;
  auto alloc = [&](size_t bytes) {
    char* p = ws + off;
    off += (bytes + 255) & ~(size_t)255;
    return p;
  };
  const size_t NF2 = (size_t)N_NODES * FDIM * 2;
  unsigned short* XAh = (unsigned short*)alloc(NF2);
  unsigned short* XAl = (unsigned short*)alloc(NF2);
  unsigned short* XBh = (unsigned short*)alloc(NF2);
  unsigned short* XBl = (unsigned short*)alloc(NF2);
  unsigned short* agh = (unsigned short*)alloc(NF2);
  unsigned short* agl = (unsigned short*)alloc(NF2);
  unsigned short* wthi = (unsigned short*)alloc((size_t)N_LAYERS * 2 * FDIM * FDIM * 2);
  unsigned short* wtlo = (unsigned short*)alloc((size_t)N_LAYERS * 2 * FDIM * FDIM * 2);
  float* deg    = (float*)alloc((size_t)N_NODES * 4);
  float* dinv   = (float*)alloc((size_t)N_NODES * 4);
  int*   cnt    = (int*)alloc((size_t)N_NODES * 4);
  int*   offs   = (int*)alloc((size_t)(N_NODES + 1) * 4);
  int*   cursor = (int*)alloc((size_t)N_NODES * 4);
  int*   src_s  = (int*)alloc((size_t)N_EDGES * 4);
  float* norm_s = (float*)alloc((size_t)N_EDGES * 4);
  int*   bsum   = (int*)alloc((size_t)NB_SCAN * 4);
  int*   bpre   = (int*)alloc((size_t)NB_SCAN * 4);

  hipMemsetAsync(deg, 0, (size_t)N_NODES * 4, stream);
  hipMemsetAsync(cnt, 0, (size_t)N_NODES * 4, stream);

  deg_count_kernel<<<(N_EDGES + 255) / 256, 256, 0, stream>>>(dst, ea, deg, cnt, N_EDGES);
  dinv_kernel<<<(N_NODES + 255) / 256, 256, 0, stream>>>(deg, dinv, N_NODES);
  blocksum_kernel<<<NB_SCAN, 256, 0, stream>>>(cnt, bsum, N_NODES);
  scanb_kernel<<<1, 256, 0, stream>>>(bsum, bpre, offs + N_NODES);
  offs_kernel<<<NB_SCAN, 256, 0, stream>>>(cnt, bpre, offs, cursor, N_NODES);
  scatter_kernel<<<(N_EDGES + 255) / 256, 256, 0, stream>>>(src, dst, ea, dinv, cursor,
                                                            src_s, norm_s, N_EDGES);
  wsplit_kernel<<<6 * 64, 256, 0, stream>>>(Wi_a, Wr_a, wthi, wtlo);
  int n4 = N_NODES * FDIM / 4;
  split_kernel<<<(n4 + 255) / 256, 256, 0, stream>>>(x0, XAh, XAl, n4);

  const size_t WMAT = (size_t)FDIM * FDIM;
  int nrow = (N_NODES + 127) / 128;
  dim3 ggrid(nrow * 2);
  unsigned short* curh = XAh; unsigned short* curl = XAl;
  unsigned short* nxth = XBh; unsigned short* nxtl = XBl;
  for (int l = 0; l < N_LAYERS; ++l) {
    agg_kernel<<<(N_NODES + 7) / 8, 256, 0, stream>>>(curh, norm_s, src_s, offs,
                                                      agh, agl, N_NODES);
    int writeFinal = (l == N_LAYERS - 1) ? 1 : 0;
    gemm_dual_kernel<<<ggrid, 256, 0, stream>>>(
        agh, agl, curh, curl,
        wthi + (size_t)(l * 2) * WMAT, wtlo + (size_t)(l * 2) * WMAT,
        wthi + (size_t)(l * 2 + 1) * WMAT, wtlo + (size_t)(l * 2 + 1) * WMAT,
        b_a + (size_t)l * FDIM,
        nxth, nxtl, out, writeFinal, N_NODES);
    unsigned short* th = curh; unsigned short* tl = curl;
    curh = nxth; curl = nxtl; nxth = th; nxtl = tl;
  }
}

// Round 9
// 627.898 us; speedup vs baseline: 1.2087x; 1.2087x over previous
//
#include <hip/hip_runtime.h>
#include <hip/hip_bf16.h>

#define N_NODES 50000
#define N_EDGES 800000
#define FDIM 256
#define N_LAYERS 3
#define NB_SCAN ((N_NODES + 255) / 256)

typedef __attribute__((ext_vector_type(8))) short bf16x8;
typedef __attribute__((ext_vector_type(8))) unsigned short u16x8;
typedef __attribute__((ext_vector_type(4))) float f32x4;

// RNE fp32 -> bf16 bit conversion (inputs finite)
__device__ inline unsigned short f2bf(float f) {
  unsigned int u = __float_as_uint(f);
  unsigned int r = u + 0x7FFFu + ((u >> 16) & 1u);
  return (unsigned short)(r >> 16);
}
__device__ inline float bf2f(unsigned short s) {
  return __uint_as_float(((unsigned int)s) << 16);
}
__device__ inline void split2(float f, unsigned short& h, unsigned short& l) {
  h = f2bf(f);
  l = f2bf(f - bf2f(h));
}

#define GLOAD16(g, l) __builtin_amdgcn_global_load_lds( \
    (const __attribute__((address_space(1))) void*)(g), \
    (__attribute__((address_space(3))) void*)(l), 16, 0, 0)

// ---------------- preprocessing (once per call; layer-invariant) ----------------

__global__ void deg_count_kernel(const int* __restrict__ dst,
                                 const float* __restrict__ w,
                                 float* __restrict__ deg,
                                 int* __restrict__ cnt, int E) {
  int e = blockIdx.x * blockDim.x + threadIdx.x;
  if (e < E) {
    int d = dst[e];
    atomicAdd(&deg[d], w[e]);
    atomicAdd(&cnt[d], 1);
  }
}

__global__ void dinv_kernel(const float* __restrict__ deg,
                            float* __restrict__ dinv, int n) {
  int i = blockIdx.x * blockDim.x + threadIdx.x;
  if (i < n) {
    float d = deg[i];
    dinv[i] = (d > 0.f) ? (1.f / sqrtf(d)) : 0.f;
  }
}

// multi-block scan: per-block sums -> 1-block scan of sums -> per-block offsets
__global__ __launch_bounds__(256)
void blocksum_kernel(const int* __restrict__ cnt, int* __restrict__ bsum, int n) {
  int b = blockIdx.x;
  int t = threadIdx.x;
  int i = b * 256 + t;
  int v = (i < n) ? cnt[i] : 0;
  #pragma unroll
  for (int d = 1; d < 64; d <<= 1) v += __shfl_xor(v, d, 64);
  __shared__ int ws[4];
  if ((t & 63) == 0) ws[t >> 6] = v;
  __syncthreads();
  if (t == 0) bsum[b] = ws[0] + ws[1] + ws[2] + ws[3];
}

__global__ __launch_bounds__(256)
void scanb_kernel(const int* __restrict__ bsum, int* __restrict__ bpre,
                  int* __restrict__ offs_end) {
  int t = threadIdx.x;
  int lane = t & 63, wid = t >> 6;
  int v = (t < NB_SCAN) ? bsum[t] : 0;
  int incl = v;
  #pragma unroll
  for (int d = 1; d < 64; d <<= 1) {
    int tmp = __shfl_up(incl, d, 64);
    if (lane >= d) incl += tmp;
  }
  __shared__ int wsum[4];
  if (lane == 63) wsum[wid] = incl;
  __syncthreads();
  if (t == 0) {
    int s = 0;
    #pragma unroll
    for (int k = 0; k < 4; ++k) { int tt = wsum[k]; wsum[k] = s; s += tt; }
  }
  __syncthreads();
  int excl = incl - v + wsum[wid];
  if (t < NB_SCAN) bpre[t] = excl;
  if (t == NB_SCAN - 1) *offs_end = excl + v;
}

__global__ __launch_bounds__(256)
void offs_kernel(const int* __restrict__ cnt, const int* __restrict__ bpre,
                 int* __restrict__ offs, int* __restrict__ cursor, int n) {
  int b = blockIdx.x;
  int t = threadIdx.x;
  int lane = t & 63, wid = t >> 6;
  int i = b * 256 + t;
  int v = (i < n) ? cnt[i] : 0;
  int incl = v;
  #pragma unroll
  for (int d = 1; d < 64; d <<= 1) {
    int tmp = __shfl_up(incl, d, 64);
    if (lane >= d) incl += tmp;
  }
  __shared__ int wsum[4];
  if (lane == 63) wsum[wid] = incl;
  __syncthreads();
  if (t == 0) {
    int s = 0;
    #pragma unroll
    for (int k = 0; k < 4; ++k) { int tt = wsum[k]; wsum[k] = s; s += tt; }
  }
  __syncthreads();
  int excl = incl - v + wsum[wid] + bpre[b];
  if (i < n) { offs[i] = excl; cursor[i] = excl; }
}

__global__ void scatter_kernel(const int* __restrict__ src,
                               const int* __restrict__ dst,
                               const float* __restrict__ w,
                               const float* __restrict__ dinv,
                               int* __restrict__ cursor,
                               int* __restrict__ src_s,
                               float* __restrict__ norm_s, int E) {
  int e = blockIdx.x * blockDim.x + threadIdx.x;
  if (e < E) {
    int s = src[e], d = dst[e];
    int pos = atomicAdd(&cursor[d], 1);
    src_s[pos] = s;
    norm_s[pos] = dinv[s] * w[e] * dinv[d];
  }
}

// split x0 -> hi/lo bf16
__global__ void split_kernel(const float* __restrict__ x,
                             unsigned short* __restrict__ xhi,
                             unsigned short* __restrict__ xlo, int n4) {
  int i = blockIdx.x * blockDim.x + threadIdx.x;
  if (i < n4) {
    float4 v = reinterpret_cast<const float4*>(x)[i];
    ushort4 h, l;
    split2(v.x, h.x, l.x);
    split2(v.y, h.y, l.y);
    split2(v.z, h.z, l.z);
    split2(v.w, h.w, l.w);
    reinterpret_cast<ushort4*>(xhi)[i] = h;
    reinterpret_cast<ushort4*>(xlo)[i] = l;
  }
}

// transpose + split weights: Wt[mat][n][k] = W[mat][k][n], mat = layer*2 + {Wi,Wr}
__global__ __launch_bounds__(256)
void wsplit_kernel(const float* __restrict__ Wi_a,
                   const float* __restrict__ Wr_a,
                   unsigned short* __restrict__ wthi,
                   unsigned short* __restrict__ wtlo) {
  __shared__ float tile[32][33];
  int m6 = blockIdx.x >> 6;            // 0..5
  int tid = blockIdx.x & 63;
  int tk = (tid >> 3) * 32;
  int tn = (tid & 7) * 32;
  int layer = m6 >> 1;
  const float* W = ((m6 & 1) ? Wr_a : Wi_a) + (size_t)layer * FDIM * FDIM;
  int t = threadIdx.x;
  int lr = t >> 3;            // 0..31
  int lc = (t & 7) * 4;       // 0..28
  float4 v = *reinterpret_cast<const float4*>(W + (size_t)(tk + lr) * FDIM + tn + lc);
  tile[lr][lc + 0] = v.x; tile[lr][lc + 1] = v.y;
  tile[lr][lc + 2] = v.z; tile[lr][lc + 3] = v.w;
  __syncthreads();
  ushort4 h, l;
  split2(tile[lc + 0][lr], h.x, l.x);
  split2(tile[lc + 1][lr], h.y, l.y);
  split2(tile[lc + 2][lr], h.z, l.z);
  split2(tile[lc + 3][lr], h.w, l.w);
  size_t o = ((size_t)m6 * FDIM + tn + lr) * FDIM + tk + lc;
  *reinterpret_cast<ushort4*>(wthi + o) = h;
  *reinterpret_cast<ushort4*>(wtlo + o) = l;
}

// ---------------- aggregation on x: aggx = A_norm @ x -------------------------
// 2 nodes per wave: 32 lanes x ushort8 (16B) per row; unroll 8 for latency ILP.
// fp32 accum; writes aggx as split hi/lo bf16.

__global__ __launch_bounds__(256)
void agg_kernel(const unsigned short* __restrict__ xh,
                const float* __restrict__ norm_s,
                const int* __restrict__ src_s,
                const int* __restrict__ offs,
                unsigned short* __restrict__ agh,
                unsigned short* __restrict__ agl, int n) {
  int t = threadIdx.x;
  int lane = t & 63;
  int node = blockIdx.x * 8 + ((t >> 6) << 1) + (lane >> 5);
  if (node >= n) return;
  int fl = lane & 31;                 // this lane owns feats [fl*8, fl*8+8)
  int beg = offs[node];
  int end = offs[node + 1];
  float a[8];
  #pragma unroll
  for (int f = 0; f < 8; ++f) a[f] = 0.f;
  const unsigned short* xbase = xh + fl * 8;
  int j = beg;
  for (; j + 8 <= end; j += 8) {
    int sj[8];
    float wj[8];
    #pragma unroll
    for (int u = 0; u < 8; ++u) { sj[u] = src_s[j + u]; wj[u] = norm_s[j + u]; }
    u16x8 v[8];
    #pragma unroll
    for (int u = 0; u < 8; ++u)
      v[u] = *reinterpret_cast<const u16x8*>(xbase + (size_t)sj[u] * FDIM);
    #pragma unroll
    for (int u = 0; u < 8; ++u)
      #pragma unroll
      for (int f = 0; f < 8; ++f)
        a[f] += wj[u] * bf2f(v[u][f]);
  }
  for (; j < end; ++j) {
    int s = src_s[j];
    float wv = norm_s[j];
    u16x8 v = *reinterpret_cast<const u16x8*>(xbase + (size_t)s * FDIM);
    #pragma unroll
    for (int f = 0; f < 8; ++f) a[f] += wv * bf2f(v[f]);
  }
  u16x8 hh, ll;
  #pragma unroll
  for (int f = 0; f < 8; ++f) {
    unsigned short h, l;
    split2(a[f], h, l);
    hh[f] = h; ll[f] = l;
  }
  size_t base = (size_t)node * FDIM + fl * 8;
  *reinterpret_cast<u16x8*>(agh + base) = hh;
  *reinterpret_cast<u16x8*>(agl + base) = ll;
}

// ------- fused dual-A GEMM: xnext = relu(aggx@Wi + x@Wr + b), split output ----
// Round-7 structure (85 us measured): 128x128 tile, BK=32, 4 waves (2x2),
// 4x4 16x16x32 frags, 3-term split per side. Single 64KB LDS buffer; per
// K-step: ds_read ALL frags -> lgkmcnt(0)+raw s_barrier -> issue next-step
// global_load_lds (overlaps MFMA) -> 96 MFMA. Top-of-step __syncthreads is the
// single vmcnt drain. NEW: T1 bijective XCD swizzle (m204) so paired blocks
// (wgid 2k,2k+1 sharing an A-panel) land on the SAME XCD -> A re-read is L2-hit.

#define STAGE_TILE(TI, GPTR, ROWB, CLAMP, K0)                                     \
  {                                                                               \
    int s0_ = t;                                                                  \
    int rr_ = s0_ >> 2;                                                           \
    int sl_ = (s0_ & 3) ^ ((rr_ >> 1) & 3);                                       \
    int r2_ = (ROWB) + rr_; if (CLAMP && r2_ >= M) r2_ = M - 1;                   \
    GLOAD16((GPTR) + (size_t)r2_ * FDIM + (K0) + sl_ * 8,                         \
            smem + (TI) * 8192 + s0_ * 16);                                       \
    int s1_ = t + 256;                                                            \
    rr_ = s1_ >> 2;                                                               \
    sl_ = (s1_ & 3) ^ ((rr_ >> 1) & 3);                                           \
    r2_ = (ROWB) + rr_; if (CLAMP && r2_ >= M) r2_ = M - 1;                       \
    GLOAD16((GPTR) + (size_t)r2_ * FDIM + (K0) + sl_ * 8,                         \
            smem + (TI) * 8192 + s1_ * 16);                                       \
  }

#define STAGE_ALL(K0)                      \
  STAGE_TILE(0, agh, rowBase, 1, K0);      \
  STAGE_TILE(1, agl, rowBase, 1, K0);      \
  STAGE_TILE(2, xh, rowBase, 1, K0);       \
  STAGE_TILE(3, xl, rowBase, 1, K0);       \
  STAGE_TILE(4, wih, nBase, 0, K0);        \
  STAGE_TILE(5, wil, nBase, 0, K0);        \
  STAGE_TILE(6, wrh, nBase, 0, K0);        \
  STAGE_TILE(7, wrl, nBase, 0, K0);

__global__ __launch_bounds__(256, 2)
void gemm_dual_kernel(const unsigned short* __restrict__ agh,
                      const unsigned short* __restrict__ agl,
                      const unsigned short* __restrict__ xh,
                      const unsigned short* __restrict__ xl,
                      const unsigned short* __restrict__ wih,
                      const unsigned short* __restrict__ wil,
                      const unsigned short* __restrict__ wrh,
                      const unsigned short* __restrict__ wrl,
                      const float* __restrict__ bias,
                      unsigned short* __restrict__ oh,
                      unsigned short* __restrict__ ol,
                      float* __restrict__ ofinal,
                      int writeFinal, int M) {
  __shared__ __align__(16) unsigned char smem[65536];
  const int t = threadIdx.x;
  const int lane = t & 63;
  const int w = t >> 6;

  // T1 bijective XCD swizzle (m204): hw-consecutive-on-one-XCD -> contiguous wgid
  const int nwg = gridDim.x;
  const int bq = nwg >> 3, br = nwg & 7;
  const int xcd = blockIdx.x & 7;
  const int idx = blockIdx.x >> 3;
  const int wgid = (xcd < br ? xcd * (bq + 1) : br * (bq + 1) + (xcd - br) * bq) + idx;
  const int rowBase = (wgid >> 1) * 128;
  const int nBase = (wgid & 1) * 128;

  const int wm = (w >> 1) * 64;
  const int wn = (w & 1) * 64;

  f32x4 acc[4][4];
  #pragma unroll
  for (int i = 0; i < 4; ++i)
    #pragma unroll
    for (int j = 0; j < 4; ++j)
      acc[i][j] = (f32x4)(0.f);

  // prologue: stage K-step 0
  STAGE_ALL(0);

  for (int s = 0; s < 8; ++s) {
    __syncthreads();   // drains vmcnt(0): staged data landed for this step

    const int q = lane >> 4;
    bf16x8 fah[4], fal[4], fxh[4], fxl[4];
    bf16x8 bih[4], bil[4], brh[4], brl[4];
    #pragma unroll
    for (int i = 0; i < 4; ++i) {
      int R = wm + i * 16 + (lane & 15);
      int offA = R * 64 + ((q ^ ((R >> 1) & 3)) * 16);
      fah[i] = *reinterpret_cast<const bf16x8*>(smem + offA);
      fal[i] = *reinterpret_cast<const bf16x8*>(smem + 8192 + offA);
      fxh[i] = *reinterpret_cast<const bf16x8*>(smem + 16384 + offA);
      fxl[i] = *reinterpret_cast<const bf16x8*>(smem + 24576 + offA);
      int Rb = wn + i * 16 + (lane & 15);
      int offB = Rb * 64 + ((q ^ ((Rb >> 1) & 3)) * 16);
      bih[i] = *reinterpret_cast<const bf16x8*>(smem + 32768 + offB);
      bil[i] = *reinterpret_cast<const bf16x8*>(smem + 40960 + offB);
      brh[i] = *reinterpret_cast<const bf16x8*>(smem + 49152 + offB);
      brl[i] = *reinterpret_cast<const bf16x8*>(smem + 57344 + offB);
    }
    // all LDS reads in registers before the buffer is overwritten
    asm volatile("s_waitcnt lgkmcnt(0)" ::: "memory");
    __builtin_amdgcn_sched_barrier(0);
    __builtin_amdgcn_s_barrier();      // raw barrier: no vmcnt drain
    __builtin_amdgcn_sched_barrier(0);

    if (s < 7) {
      int k1 = (s + 1) * 32;
      STAGE_ALL(k1);                   // flies under the MFMA cluster below
    }

    #pragma unroll
    for (int j = 0; j < 4; ++j) {
      #pragma unroll
      for (int i = 0; i < 4; ++i) {
        acc[i][j] = __builtin_amdgcn_mfma_f32_16x16x32_bf16(fal[i], bih[j], acc[i][j], 0, 0, 0);
        acc[i][j] = __builtin_amdgcn_mfma_f32_16x16x32_bf16(fah[i], bil[j], acc[i][j], 0, 0, 0);
        acc[i][j] = __builtin_amdgcn_mfma_f32_16x16x32_bf16(fah[i], bih[j], acc[i][j], 0, 0, 0);
        acc[i][j] = __builtin_amdgcn_mfma_f32_16x16x32_bf16(fxl[i], brh[j], acc[i][j], 0, 0, 0);
        acc[i][j] = __builtin_amdgcn_mfma_f32_16x16x32_bf16(fxh[i], brl[j], acc[i][j], 0, 0, 0);
        acc[i][j] = __builtin_amdgcn_mfma_f32_16x16x32_bf16(fxh[i], brh[j], acc[i][j], 0, 0, 0);
      }
    }
  }

  const int cr = lane & 15;
  const int r4 = (lane >> 4) * 4;
  #pragma unroll
  for (int i = 0; i < 4; ++i)
    #pragma unroll
    for (int j = 0; j < 4; ++j) {
      int col = nBase + wn + j * 16 + cr;
      float badd = bias[col];
      #pragma unroll
      for (int e = 0; e < 4; ++e) {
        int row = rowBase + wm + i * 16 + r4 + e;
        if (row < M) {
          float val = fmaxf(acc[i][j][e] + badd, 0.f);
          size_t o = (size_t)row * FDIM + col;
          if (writeFinal) {
            ofinal[o] = val;
          } else {
            unsigned short hh, ll;
            split2(val, hh, ll);
            oh[o] = hh;
            ol[o] = ll;
          }
        }
      }
    }
}

// ---------------- launch ----------------

extern "C" void kernel_launch(void* const* d_in, const int* in_sizes, int n_in,
                              void* d_out, int out_size, void* d_ws, size_t ws_size,
                              hipStream_t stream) {
  (void)in_sizes; (void)n_in; (void)out_size; (void)ws_size;
  const float* x0   = (const float*)d_in[0];
  const int*   ei   = (const int*)d_in[1];
  const float* ea   = (const float*)d_in[2];
  const float* Wi_a = (const float*)d_in[3];
  const float* Wr_a = (const float*)d_in[4];
  const float* b_a  = (const float*)d_in[5];
  float* out = (float*)d_out;

  const int* src = ei;
  const int* dst = ei + N_EDGES;

  char* ws = (char*)d_ws;
  size_t off = 0;
  auto alloc = [&](size_t bytes) {
    char* p = ws + off;
    off += (bytes + 255) & ~(size_t)255;
    return p;
  };
  const size_t NF2 = (size_t)N_NODES * FDIM * 2;
  unsigned short* XAh = (unsigned short*)alloc(NF2);
  unsigned short* XAl = (unsigned short*)alloc(NF2);
  unsigned short* XBh = (unsigned short*)alloc(NF2);
  unsigned short* XBl = (unsigned short*)alloc(NF2);
  unsigned short* agh = (unsigned short*)alloc(NF2);
  unsigned short* agl = (unsigned short*)alloc(NF2);
  unsigned short* wthi = (unsigned short*)alloc((size_t)N_LAYERS * 2 * FDIM * FDIM * 2);
  unsigned short* wtlo = (unsigned short*)alloc((size_t)N_LAYERS * 2 * FDIM * FDIM * 2);
  float* deg    = (float*)alloc((size_t)N_NODES * 4);
  float* dinv   = (float*)alloc((size_t)N_NODES * 4);
  int*   cnt    = (int*)alloc((size_t)N_NODES * 4);
  int*   offs   = (int*)alloc((size_t)(N_NODES + 1) * 4);
  int*   cursor = (int*)alloc((size_t)N_NODES * 4);
  int*   src_s  = (int*)alloc((size_t)N_EDGES * 4);
  float* norm_s = (float*)alloc((size_t)N_EDGES * 4);
  int*   bsum   = (int*)alloc((size_t)NB_SCAN * 4);
  int*   bpre   = (int*)alloc((size_t)NB_SCAN * 4);

  hipMemsetAsync(deg, 0, (size_t)N_NODES * 4, stream);
  hipMemsetAsync(cnt, 0, (size_t)N_NODES * 4, stream);

  deg_count_kernel<<<(N_EDGES + 255) / 256, 256, 0, stream>>>(dst, ea, deg, cnt, N_EDGES);
  dinv_kernel<<<(N_NODES + 255) / 256, 256, 0, stream>>>(deg, dinv, N_NODES);
  blocksum_kernel<<<NB_SCAN, 256, 0, stream>>>(cnt, bsum, N_NODES);
  scanb_kernel<<<1, 256, 0, stream>>>(bsum, bpre, offs + N_NODES);
  offs_kernel<<<NB_SCAN, 256, 0, stream>>>(cnt, bpre, offs, cursor, N_NODES);
  scatter_kernel<<<(N_EDGES + 255) / 256, 256, 0, stream>>>(src, dst, ea, dinv, cursor,
                                                            src_s, norm_s, N_EDGES);
  wsplit_kernel<<<6 * 64, 256, 0, stream>>>(Wi_a, Wr_a, wthi, wtlo);
  int n4 = N_NODES * FDIM / 4;
  split_kernel<<<(n4 + 255) / 256, 256, 0, stream>>>(x0, XAh, XAl, n4);

  const size_t WMAT = (size_t)FDIM * FDIM;
  int nrow = (N_NODES + 127) / 128;
  dim3 ggrid(nrow * 2);
  unsigned short* curh = XAh; unsigned short* curl = XAl;
  unsigned short* nxth = XBh; unsigned short* nxtl = XBl;
  for (int l = 0; l < N_LAYERS; ++l) {
    agg_kernel<<<(N_NODES + 7) / 8, 256, 0, stream>>>(curh, norm_s, src_s, offs,
                                                      agh, agl, N_NODES);
    int writeFinal = (l == N_LAYERS - 1) ? 1 : 0;
    gemm_dual_kernel<<<ggrid, 256, 0, stream>>>(
        agh, agl, curh, curl,
        wthi + (size_t)(l * 2) * WMAT, wtlo + (size_t)(l * 2) * WMAT,
        wthi + (size_t)(l * 2 + 1) * WMAT, wtlo + (size_t)(l * 2 + 1) * WMAT,
        b_a + (size_t)l * FDIM,
        nxth, nxtl, out, writeFinal, N_NODES);
    unsigned short* th = curh; unsigned short* tl = curl;
    curh = nxth; curl = nxtl; nxth = th; nxtl = tl;
  }
}

// Round 11
// 600.776 us; speedup vs baseline: 1.2633x; 1.0451x over previous
//
#include <hip/hip_runtime.h>
#include <hip/hip_bf16.h>

#define N_NODES 50000
#define N_EDGES 800000
#define FDIM 256
#define N_LAYERS 3
#define NB_SCAN ((N_NODES + 255) / 256)

typedef __attribute__((ext_vector_type(8))) short bf16x8;
typedef __attribute__((ext_vector_type(8))) unsigned short u16x8;
typedef __attribute__((ext_vector_type(4))) float f32x4;

// RNE fp32 -> bf16 bit conversion (inputs finite)
__device__ inline unsigned short f2bf(float f) {
  unsigned int u = __float_as_uint(f);
  unsigned int r = u + 0x7FFFu + ((u >> 16) & 1u);
  return (unsigned short)(r >> 16);
}
__device__ inline float bf2f(unsigned short s) {
  return __uint_as_float(((unsigned int)s) << 16);
}
__device__ inline void split2(float f, unsigned short& h, unsigned short& l) {
  h = f2bf(f);
  l = f2bf(f - bf2f(h));
}

#define GLOAD16(g, l) __builtin_amdgcn_global_load_lds( \
    (const __attribute__((address_space(1))) void*)(g), \
    (__attribute__((address_space(3))) void*)(l), 16, 0, 0)

// ---------------- preprocessing (once per call; layer-invariant) ----------------

// 1 atomic per edge (count only); deg computed later from CSR without atomics
__global__ void deg_count_kernel(const int* __restrict__ dst,
                                 int* __restrict__ cnt, int E) {
  int e = blockIdx.x * blockDim.x + threadIdx.x;
  if (e < E) atomicAdd(&cnt[dst[e]], 1);
}

// multi-block scan: per-block sums -> 1-block scan of sums -> per-block offsets
__global__ __launch_bounds__(256)
void blocksum_kernel(const int* __restrict__ cnt, int* __restrict__ bsum, int n) {
  int b = blockIdx.x;
  int t = threadIdx.x;
  int i = b * 256 + t;
  int v = (i < n) ? cnt[i] : 0;
  #pragma unroll
  for (int d = 1; d < 64; d <<= 1) v += __shfl_xor(v, d, 64);
  __shared__ int ws[4];
  if ((t & 63) == 0) ws[t >> 6] = v;
  __syncthreads();
  if (t == 0) bsum[b] = ws[0] + ws[1] + ws[2] + ws[3];
}

__global__ __launch_bounds__(256)
void scanb_kernel(const int* __restrict__ bsum, int* __restrict__ bpre,
                  int* __restrict__ offs_end) {
  int t = threadIdx.x;
  int lane = t & 63, wid = t >> 6;
  int v = (t < NB_SCAN) ? bsum[t] : 0;
  int incl = v;
  #pragma unroll
  for (int d = 1; d < 64; d <<= 1) {
    int tmp = __shfl_up(incl, d, 64);
    if (lane >= d) incl += tmp;
  }
  __shared__ int wsum[4];
  if (lane == 63) wsum[wid] = incl;
  __syncthreads();
  if (t == 0) {
    int s = 0;
    #pragma unroll
    for (int k = 0; k < 4; ++k) { int tt = wsum[k]; wsum[k] = s; s += tt; }
  }
  __syncthreads();
  int excl = incl - v + wsum[wid];
  if (t < NB_SCAN) bpre[t] = excl;
  if (t == NB_SCAN - 1) *offs_end = excl + v;
}

__global__ __launch_bounds__(256)
void offs_kernel(const int* __restrict__ cnt, const int* __restrict__ bpre,
                 int* __restrict__ offs, int* __restrict__ cursor, int n) {
  int b = blockIdx.x;
  int t = threadIdx.x;
  int lane = t & 63, wid = t >> 6;
  int i = b * 256 + t;
  int v = (i < n) ? cnt[i] : 0;
  int incl = v;
  #pragma unroll
  for (int d = 1; d < 64; d <<= 1) {
    int tmp = __shfl_up(incl, d, 64);
    if (lane >= d) incl += tmp;
  }
  __shared__ int wsum[4];
  if (lane == 63) wsum[wid] = incl;
  __syncthreads();
  if (t == 0) {
    int s = 0;
    #pragma unroll
    for (int k = 0; k < 4; ++k) { int tt = wsum[k]; wsum[k] = s; s += tt; }
  }
  __syncthreads();
  int excl = incl - v + wsum[wid] + bpre[b];
  if (i < n) { offs[i] = excl; cursor[i] = excl; }
}

// bucket edges by dst; store src index and raw edge weight (norm comes later)
__global__ void scatter_kernel(const int* __restrict__ src,
                               const int* __restrict__ dst,
                               const float* __restrict__ w,
                               int* __restrict__ cursor,
                               int* __restrict__ src_s,
                               float* __restrict__ w_s, int E) {
  int e = blockIdx.x * blockDim.x + threadIdx.x;
  if (e < E) {
    int d = dst[e];
    int pos = atomicAdd(&cursor[d], 1);
    src_s[pos] = src[e];
    w_s[pos] = w[e];
  }
}

// deg = CSR segmented sum of w_s (no atomics); dinv folded in
__global__ void degdinv_kernel(const float* __restrict__ w_s,
                               const int* __restrict__ offs,
                               float* __restrict__ dinv, int n) {
  int i = blockIdx.x * blockDim.x + threadIdx.x;
  if (i < n) {
    int beg = offs[i], end = offs[i + 1];
    float s = 0.f;
    for (int j = beg; j < end; ++j) s += w_s[j];
    dinv[i] = (s > 0.f) ? (1.f / sqrtf(s)) : 0.f;
  }
}

// norm_s[j] = w_s[j] * dinv[src_s[j]] * dinv[dstnode]  (same product as before)
__global__ void norm_kernel(const float* __restrict__ w_s,
                            const int* __restrict__ src_s,
                            const int* __restrict__ offs,
                            const float* __restrict__ dinv,
                            float* __restrict__ norm_s, int n) {
  int i = blockIdx.x * blockDim.x + threadIdx.x;
  if (i < n) {
    int beg = offs[i], end = offs[i + 1];
    float dn = dinv[i];
    for (int j = beg; j < end; ++j)
      norm_s[j] = dinv[src_s[j]] * w_s[j] * dn;
  }
}

// split x0 -> hi/lo bf16
__global__ void split_kernel(const float* __restrict__ x,
                             unsigned short* __restrict__ xhi,
                             unsigned short* __restrict__ xlo, int n4) {
  int i = blockIdx.x * blockDim.x + threadIdx.x;
  if (i < n4) {
    float4 v = reinterpret_cast<const float4*>(x)[i];
    ushort4 h, l;
    split2(v.x, h.x, l.x);
    split2(v.y, h.y, l.y);
    split2(v.z, h.z, l.z);
    split2(v.w, h.w, l.w);
    reinterpret_cast<ushort4*>(xhi)[i] = h;
    reinterpret_cast<ushort4*>(xlo)[i] = l;
  }
}

// transpose + split weights: Wt[mat][n][k] = W[mat][k][n], mat = layer*2 + {Wi,Wr}
__global__ __launch_bounds__(256)
void wsplit_kernel(const float* __restrict__ Wi_a,
                   const float* __restrict__ Wr_a,
                   unsigned short* __restrict__ wthi,
                   unsigned short* __restrict__ wtlo) {
  __shared__ float tile[32][33];
  int m6 = blockIdx.x >> 6;            // 0..5
  int tid = blockIdx.x & 63;
  int tk = (tid >> 3) * 32;
  int tn = (tid & 7) * 32;
  int layer = m6 >> 1;
  const float* W = ((m6 & 1) ? Wr_a : Wi_a) + (size_t)layer * FDIM * FDIM;
  int t = threadIdx.x;
  int lr = t >> 3;            // 0..31
  int lc = (t & 7) * 4;       // 0..28
  float4 v = *reinterpret_cast<const float4*>(W + (size_t)(tk + lr) * FDIM + tn + lc);
  tile[lr][lc + 0] = v.x; tile[lr][lc + 1] = v.y;
  tile[lr][lc + 2] = v.z; tile[lr][lc + 3] = v.w;
  __syncthreads();
  ushort4 h, l;
  split2(tile[lc + 0][lr], h.x, l.x);
  split2(tile[lc + 1][lr], h.y, l.y);
  split2(tile[lc + 2][lr], h.z, l.z);
  split2(tile[lc + 3][lr], h.w, l.w);
  size_t o = ((size_t)m6 * FDIM + tn + lr) * FDIM + tk + lc;
  *reinterpret_cast<ushort4*>(wthi + o) = h;
  *reinterpret_cast<ushort4*>(wtlo + o) = l;
}

// ---------------- aggregation on x: aggx = A_norm @ x -------------------------
// 2 nodes per wave: 32 lanes x ushort8 (16B) per row; unroll 8 for latency ILP.

__global__ __launch_bounds__(256)
void agg_kernel(const unsigned short* __restrict__ xh,
                const float* __restrict__ norm_s,
                const int* __restrict__ src_s,
                const int* __restrict__ offs,
                unsigned short* __restrict__ agh,
                unsigned short* __restrict__ agl, int n) {
  int t = threadIdx.x;
  int lane = t & 63;
  int node = blockIdx.x * 8 + ((t >> 6) << 1) + (lane >> 5);
  if (node >= n) return;
  int fl = lane & 31;                 // this lane owns feats [fl*8, fl*8+8)
  int beg = offs[node];
  int end = offs[node + 1];
  float a[8];
  #pragma unroll
  for (int f = 0; f < 8; ++f) a[f] = 0.f;
  const unsigned short* xbase = xh + fl * 8;
  int j = beg;
  for (; j + 8 <= end; j += 8) {
    int sj[8];
    float wj[8];
    #pragma unroll
    for (int u = 0; u < 8; ++u) { sj[u] = src_s[j + u]; wj[u] = norm_s[j + u]; }
    u16x8 v[8];
    #pragma unroll
    for (int u = 0; u < 8; ++u)
      v[u] = *reinterpret_cast<const u16x8*>(xbase + (size_t)sj[u] * FDIM);
    #pragma unroll
    for (int u = 0; u < 8; ++u)
      #pragma unroll
      for (int f = 0; f < 8; ++f)
        a[f] += wj[u] * bf2f(v[u][f]);
  }
  for (; j < end; ++j) {
    int s = src_s[j];
    float wv = norm_s[j];
    u16x8 v = *reinterpret_cast<const u16x8*>(xbase + (size_t)s * FDIM);
    #pragma unroll
    for (int f = 0; f < 8; ++f) a[f] += wv * bf2f(v[f]);
  }
  u16x8 hh, ll;
  #pragma unroll
  for (int f = 0; f < 8; ++f) {
    unsigned short h, l;
    split2(a[f], h, l);
    hh[f] = h; ll[f] = l;
  }
  size_t base = (size_t)node * FDIM + fl * 8;
  *reinterpret_cast<u16x8*>(agh + base) = hh;
  *reinterpret_cast<u16x8*>(agl + base) = ll;
}

// ------- fused dual-A GEMM: xnext = relu(aggx@Wi + x@Wr + b), split output ----
// Geometry: BM=256, BN=128, BK=32, 512 threads (8 waves as 4x2, 64x64/wave).
// Staged bytes/layer: 392 blocks x 96KB x 8 steps = 301MB (was 400MB).
// 96KB single-buffer LDS: A-side 4 mats x 16KB @0..64K, B-side 4 mats x 8KB @64K+.
// Round-7 schedule: top __syncthreads = single vmcnt drain; read all frags ->
// lgkmcnt(0) + raw s_barrier -> issue next-step staging -> 96 MFMA.
// T1 bijective XCD swizzle keeps A-panel pair (wgid 2k,2k+1) on one XCD.

#define STAGE_A(TI, GPTR, K0)                                                     \
  {                                                                               \
    int s0_ = t;                                                                  \
    int rr_ = s0_ >> 2;                                                           \
    int sl_ = (s0_ & 3) ^ ((rr_ >> 1) & 3);                                       \
    int r2_ = rowBase + rr_; if (r2_ >= M) r2_ = M - 1;                           \
    GLOAD16((GPTR) + (size_t)r2_ * FDIM + (K0) + sl_ * 8,                         \
            smem + (TI) * 16384 + s0_ * 16);                                      \
    int s1_ = t + 512;                                                            \
    rr_ = s1_ >> 2;                                                               \
    sl_ = (s1_ & 3) ^ ((rr_ >> 1) & 3);                                           \
    r2_ = rowBase + rr_; if (r2_ >= M) r2_ = M - 1;                               \
    GLOAD16((GPTR) + (size_t)r2_ * FDIM + (K0) + sl_ * 8,                         \
            smem + (TI) * 16384 + s1_ * 16);                                      \
  }

#define STAGE_B(TI, GPTR, K0)                                                     \
  {                                                                               \
    int s0_ = t;                                                                  \
    int rr_ = s0_ >> 2;                                                           \
    int sl_ = (s0_ & 3) ^ ((rr_ >> 1) & 3);                                       \
    GLOAD16((GPTR) + (size_t)(nBase + rr_) * FDIM + (K0) + sl_ * 8,               \
            smem + 65536 + (TI) * 8192 + s0_ * 16);                               \
  }

#define STAGE_ALL(K0)                      \
  STAGE_A(0, agh, K0);                     \
  STAGE_A(1, agl, K0);                     \
  STAGE_A(2, xh, K0);                      \
  STAGE_A(3, xl, K0);                      \
  STAGE_B(0, wih, K0);                     \
  STAGE_B(1, wil, K0);                     \
  STAGE_B(2, wrh, K0);                     \
  STAGE_B(3, wrl, K0);

__global__ __launch_bounds__(512, 2)
void gemm_dual_kernel(const unsigned short* __restrict__ agh,
                      const unsigned short* __restrict__ agl,
                      const unsigned short* __restrict__ xh,
                      const unsigned short* __restrict__ xl,
                      const unsigned short* __restrict__ wih,
                      const unsigned short* __restrict__ wil,
                      const unsigned short* __restrict__ wrh,
                      const unsigned short* __restrict__ wrl,
                      const float* __restrict__ bias,
                      unsigned short* __restrict__ oh,
                      unsigned short* __restrict__ ol,
                      float* __restrict__ ofinal,
                      int writeFinal, int M) {
  __shared__ __align__(16) unsigned char smem[98304];   // 64KB A + 32KB B
  const int t = threadIdx.x;
  const int lane = t & 63;
  const int w = t >> 6;

  // T1 bijective XCD swizzle (m204)
  const int nwg = gridDim.x;
  const int bq = nwg >> 3, br = nwg & 7;
  const int xcd = blockIdx.x & 7;
  const int idx = blockIdx.x >> 3;
  const int wgid = (xcd < br ? xcd * (bq + 1) : br * (bq + 1) + (xcd - br) * bq) + idx;
  const int rowBase = (wgid >> 1) * 256;
  const int nBase = (wgid & 1) * 128;

  const int wm = (w >> 1) * 64;   // 0,64,128,192
  const int wn = (w & 1) * 64;    // 0,64

  f32x4 acc[4][4];
  #pragma unroll
  for (int i = 0; i < 4; ++i)
    #pragma unroll
    for (int j = 0; j < 4; ++j)
      acc[i][j] = (f32x4)(0.f);

  // prologue: stage K-step 0
  STAGE_ALL(0);

  for (int s = 0; s < 8; ++s) {
    __syncthreads();   // drains vmcnt(0): staged data landed for this step

    const int q = lane >> 4;
    bf16x8 fah[4], fal[4], fxh[4], fxl[4];
    bf16x8 bih[4], bil[4], brh[4], brl[4];
    #pragma unroll
    for (int i = 0; i < 4; ++i) {
      int R = wm + i * 16 + (lane & 15);
      int offA = R * 64 + ((q ^ ((R >> 1) & 3)) * 16);
      fah[i] = *reinterpret_cast<const bf16x8*>(smem + offA);
      fal[i] = *reinterpret_cast<const bf16x8*>(smem + 16384 + offA);
      fxh[i] = *reinterpret_cast<const bf16x8*>(smem + 32768 + offA);
      fxl[i] = *reinterpret_cast<const bf16x8*>(smem + 49152 + offA);
      int Rb = wn + i * 16 + (lane & 15);
      int offB = 65536 + Rb * 64 + ((q ^ ((Rb >> 1) & 3)) * 16);
      bih[i] = *reinterpret_cast<const bf16x8*>(smem + offB);
      bil[i] = *reinterpret_cast<const bf16x8*>(smem + 8192 + offB);
      brh[i] = *reinterpret_cast<const bf16x8*>(smem + 16384 + offB);
      brl[i] = *reinterpret_cast<const bf16x8*>(smem + 24576 + offB);
    }
    // all LDS reads in registers before the buffer is overwritten
    asm volatile("s_waitcnt lgkmcnt(0)" ::: "memory");
    __builtin_amdgcn_sched_barrier(0);
    __builtin_amdgcn_s_barrier();      // raw barrier: no vmcnt drain
    __builtin_amdgcn_sched_barrier(0);

    if (s < 7) {
      int k1 = (s + 1) * 32;
      STAGE_ALL(k1);                   // flies under the MFMA cluster below
    }

    #pragma unroll
    for (int j = 0; j < 4; ++j) {
      #pragma unroll
      for (int i = 0; i < 4; ++i) {
        acc[i][j] = __builtin_amdgcn_mfma_f32_16x16x32_bf16(fal[i], bih[j], acc[i][j], 0, 0, 0);
        acc[i][j] = __builtin_amdgcn_mfma_f32_16x16x32_bf16(fah[i], bil[j], acc[i][j], 0, 0, 0);
        acc[i][j] = __builtin_amdgcn_mfma_f32_16x16x32_bf16(fah[i], bih[j], acc[i][j], 0, 0, 0);
        acc[i][j] = __builtin_amdgcn_mfma_f32_16x16x32_bf16(fxl[i], brh[j], acc[i][j], 0, 0, 0);
        acc[i][j] = __builtin_amdgcn_mfma_f32_16x16x32_bf16(fxh[i], brl[j], acc[i][j], 0, 0, 0);
        acc[i][j] = __builtin_amdgcn_mfma_f32_16x16x32_bf16(fxh[i], brh[j], acc[i][j], 0, 0, 0);
      }
    }
  }

  const int cr = lane & 15;
  const int r4 = (lane >> 4) * 4;
  #pragma unroll
  for (int i = 0; i < 4; ++i)
    #pragma unroll
    for (int j = 0; j < 4; ++j) {
      int col = nBase + wn + j * 16 + cr;
      float badd = bias[col];
      #pragma unroll
      for (int e = 0; e < 4; ++e) {
        int row = rowBase + wm + i * 16 + r4 + e;
        if (row < M) {
          float val = fmaxf(acc[i][j][e] + badd, 0.f);
          size_t o = (size_t)row * FDIM + col;
          if (writeFinal) {
            ofinal[o] = val;
          } else {
            unsigned short hh, ll;
            split2(val, hh, ll);
            oh[o] = hh;
            ol[o] = ll;
          }
        }
      }
    }
}

// ---------------- launch ----------------

extern "C" void kernel_launch(void* const* d_in, const int* in_sizes, int n_in,
                              void* d_out, int out_size, void* d_ws, size_t ws_size,
                              hipStream_t stream) {
  (void)in_sizes; (void)n_in; (void)out_size; (void)ws_size;
  const float* x0   = (const float*)d_in[0];
  const int*   ei   = (const int*)d_in[1];
  const float* ea   = (const float*)d_in[2];
  const float* Wi_a = (const float*)d_in[3];
  const float* Wr_a = (const float*)d_in[4];
  const float* b_a  = (const float*)d_in[5];
  float* out = (float*)d_out;

  const int* src = ei;
  const int* dst = ei + N_EDGES;

  char* ws = (char*)d_ws;
  size_t off = 0;
  auto alloc = [&](size_t bytes) {
    char* p = ws + off;
    off += (bytes + 255) & ~(size_t)255;
    return p;
  };
  const size_t NF2 = (size_t)N_NODES * FDIM * 2;
  unsigned short* XAh = (unsigned short*)alloc(NF2);
  unsigned short* XAl = (unsigned short*)alloc(NF2);
  unsigned short* XBh = (unsigned short*)alloc(NF2);
  unsigned short* XBl = (unsigned short*)alloc(NF2);
  unsigned short* agh = (unsigned short*)alloc(NF2);
  unsigned short* agl = (unsigned short*)alloc(NF2);
  unsigned short* wthi = (unsigned short*)alloc((size_t)N_LAYERS * 2 * FDIM * FDIM * 2);
  unsigned short* wtlo = (unsigned short*)alloc((size_t)N_LAYERS * 2 * FDIM * FDIM * 2);
  float* dinv   = (float*)alloc((size_t)N_NODES * 4);
  int*   cnt    = (int*)alloc((size_t)N_NODES * 4);
  int*   offs   = (int*)alloc((size_t)(N_NODES + 1) * 4);
  int*   cursor = (int*)alloc((size_t)N_NODES * 4);
  int*   src_s  = (int*)alloc((size_t)N_EDGES * 4);
  float* w_s    = (float*)alloc((size_t)N_EDGES * 4);
  float* norm_s = (float*)alloc((size_t)N_EDGES * 4);
  int*   bsum   = (int*)alloc((size_t)NB_SCAN * 4);
  int*   bpre   = (int*)alloc((size_t)NB_SCAN * 4);

  hipMemsetAsync(cnt, 0, (size_t)N_NODES * 4, stream);

  deg_count_kernel<<<(N_EDGES + 255) / 256, 256, 0, stream>>>(dst, cnt, N_EDGES);
  blocksum_kernel<<<NB_SCAN, 256, 0, stream>>>(cnt, bsum, N_NODES);
  scanb_kernel<<<1, 256, 0, stream>>>(bsum, bpre, offs + N_NODES);
  offs_kernel<<<NB_SCAN, 256, 0, stream>>>(cnt, bpre, offs, cursor, N_NODES);
  scatter_kernel<<<(N_EDGES + 255) / 256, 256, 0, stream>>>(src, dst, ea, cursor,
                                                            src_s, w_s, N_EDGES);
  degdinv_kernel<<<(N_NODES + 255) / 256, 256, 0, stream>>>(w_s, offs, dinv, N_NODES);
  norm_kernel<<<(N_NODES + 255) / 256, 256, 0, stream>>>(w_s, src_s, offs, dinv,
                                                         norm_s, N_NODES);
  wsplit_kernel<<<6 * 64, 256, 0, stream>>>(Wi_a, Wr_a, wthi, wtlo);
  int n4 = N_NODES * FDIM / 4;
  split_kernel<<<(n4 + 255) / 256, 256, 0, stream>>>(x0, XAh, XAl, n4);

  const size_t WMAT = (size_t)FDIM * FDIM;
  int nrow = (N_NODES + 255) / 256;
  dim3 ggrid(nrow * 2);
  unsigned short* curh = XAh; unsigned short* curl = XAl;
  unsigned short* nxth = XBh; unsigned short* nxtl = XBl;
  for (int l = 0; l < N_LAYERS; ++l) {
    agg_kernel<<<(N_NODES + 7) / 8, 256, 0, stream>>>(curh, norm_s, src_s, offs,
                                                      agh, agl, N_NODES);
    int writeFinal = (l == N_LAYERS - 1) ? 1 : 0;
    gemm_dual_kernel<<<ggrid, 512, 0, stream>>>(
        agh, agl, curh, curl,
        wthi + (size_t)(l * 2) * WMAT, wtlo + (size_t)(l * 2) * WMAT,
        wthi + (size_t)(l * 2 + 1) * WMAT, wtlo + (size_t)(l * 2 + 1) * WMAT,
        b_a + (size_t)l * FDIM,
        nxth, nxtl, out, writeFinal, N_NODES);
    unsigned short* th = curh; unsigned short* tl = curl;
    curh = nxth; curl = nxtl; nxth = th; nxtl = tl;
  }
}